// Round 15
// baseline (39.397 us; speedup 1.0000x reference)
//
#include <hip/hip_runtime.h>
#include <hip/hip_bf16.h>
#include <hip/hip_fp16.h>

// AdaCoF frame interpolation. R15: R14 + pair-duplicated fp16 c2 plane.
//  R14 confirmed conflict-dword model: conflicts 8.9M -> 5.98M tracking the
//  12 -> 8 dword/tap cut; per-instruction overhead (7.3 cyc) is the random-
//  address statistical limit, so the lever is dwords/tap.
//  R15: win2[e] = half2(c2[x], c2[x+1]) (pair-duplicated): ONE dword yields
//  both x-corners of c2 -> c2 costs 2 dwords/tap (read2 offsets 0, WCOLS=53,
//  fits 8-bit imm). Total 6 dwords / 3 ds_read2_b32 per tap (was 8 / 4).
//  c2 now fp16 (+2.4e-4 err; absmax 3.9e-3, threshold 15.7e-3 -> safe).
//  Staging adds one adjacent (L1-hit) load per element for the x+1 sample.
//  Everything else R13/R14 verbatim: 2048 blocks, window-relative corner
//  math on the materialized replication-padded window, deferred
//  normalization, ws partials + combine2.
//  Tripwires: absmax <= 7e-3; conflicts ~4.5M.

#define KS 5
#define K2 25
#define PADR 2

constexpr int T_ = 2;
constexpr int B_ = 4;
constexpr int C_ = 3;
constexpr int H_ = 256;
constexpr int W_ = 256;
constexpr int HW_ = H_ * W_;
constexpr int BCHW_ = B_ * C_ * HW_;                  // 786432
constexpr float HP_MAX = (float)(H_ + 2 * PADR - 1);  // 259
constexpr float WP_MAX = (float)(W_ + 2 * PADR - 1);  // 259
constexpr float HP_M2 = (float)(H_ + 2 * PADR - 2);   // 258
constexpr float WP_M2 = (float)(W_ + 2 * PADR - 2);   // 258

constexpr int TILE_W = 32;
constexpr int TILE_H = 8;
constexpr int HALO   = 8;
constexpr int RPAD   = HALO + PADR;            // 10
constexpr int WROWS  = TILE_H + 21;            // 29
constexpr int WCOLS  = TILE_W + 21;            // 53
constexpr int PLANE  = WROWS * WCOLS;          // 1537
constexpr int NTILE  = HW_ / (TILE_W * TILE_H);  // 256

__global__ __launch_bounds__(256) void adacof_tile(
    const float* __restrict__ frames,   // [T,B,C,H,W]
    const float* __restrict__ weights,  // [B,T,K2,H,W]
    const float* __restrict__ alphas,   // [B,T,K2,H,W]
    const float* __restrict__ betas,    // [B,T,K2,H,W]
    const float* __restrict__ occl,     // [B,T,H,W]
    float* __restrict__ part)           // ws: [T,B,C,H,W]
{
    __shared__ __half2 winA[PLANE];     // (c0,c1) at x:          6.1 KB
    __shared__ __half2 win2[PLANE];     // (c2 at x, c2 at x+1):  6.1 KB

    // block decode: 2048 blocks = b(4) x tile(256) x t(2)
    const int bid  = blockIdx.x;
    const int b    = bid >> 9;
    const int rem  = bid & 511;
    const int t    = rem & 1;
    const int tile = rem >> 1;          // 0..255
    const int i0   = (tile >> 3) << 3;  // row tile * 8
    const int j0   = (tile & 7) << 5;   // col tile * 32

    const int tid = threadIdx.x;
    const int wy0 = i0 - RPAD;
    const int wx0 = j0 - RPAD;

    const float* __restrict__ fb = frames + (size_t)(t * B_ + b) * C_ * HW_;

    // ---- stage window = materialized replication-padded image ----
    for (int e = tid; e < PLANE; e += 256) {
        const int wy = e / WCOLS;               // const-div -> magic mul
        const int wx = e - wy * WCOLS;
        const int gy  = min(max(wy0 + wy, 0), H_ - 1);
        const int gx  = min(max(wx0 + wx, 0), W_ - 1);
        const int gx1 = min(max(wx0 + wx + 1, 0), W_ - 1);
        const int gr = gy << 8;
        winA[e] = __floats2half2_rn(fb[gr + gx], fb[HW_ + gr + gx]);
        win2[e] = __floats2half2_rn(fb[2 * HW_ + gr + gx], fb[2 * HW_ + gr + gx1]);
    }

    const int x = tid & 31, r = tid >> 5;
    const int i = i0 + r, j = j0 + x;
    const int ij = (i << 8) | j;

    const int btbase = ((b * T_ + t) * K2) * HW_ + ij;
    const float* __restrict__ wp = weights + btbase;
    const float* __restrict__ ap = alphas + btbase;
    const float* __restrict__ bp = betas + btbase;

    // occlusion loads issued early, consumed in epilogue
    const float o_own = occl[(b * T_ + t) * HW_ + ij];
    const float o_oth = occl[(b * T_ + (1 - t)) * HW_ + ij];

    __syncthreads();

    float wsum = 0.0f, acc0 = 0.0f, acc1 = 0.0f, acc2 = 0.0f;
    const float fi = (float)i;
    const float fj = (float)j;
    const float oy = (float)(i0 - HALO);   // window-origin offset: wyr=y0f-oy
    const float ox = (float)(j0 - HALO);

    #pragma unroll
    for (int k = 0; k < K2; ++k) {
        const float wv = wp[k * HW_];
        const float av = ap[k * HW_];
        const float bv = bp[k * HW_];
        const float ew = __expf(wv);     // no max-subtraction: N(0,1), f32-safe
        wsum += ew;

        const int kd = k / KS;
        const float dy = (float)kd;
        const float dx = (float)(k - kd * KS);

        // reference coordinate clips only (padded space [0,259], y0<=258)
        const float y2  = fminf(fmaxf(av + (dy + fi), 0.0f), HP_MAX);
        const float x2  = fminf(fmaxf(bv + (dx + fj), 0.0f), WP_MAX);
        const float y0f = fminf(floorf(y2), HP_M2);
        const float x0f = fminf(floorf(x2), WP_M2);
        const float fy  = y2 - y0f;
        const float fx  = x2 - x0f;

        // window-relative corner index (win IS replication-padded; R13-exact)
        const int iy = (int)(y0f - oy);
        const int ix = (int)(x0f - ox);
        const int l  = iy * WCOLS + ix;

        // factored bilinear weights (6 ops)
        const float fyw = fy * ew;
        const float ey0 = ew - fyw;
        const float w01 = fx * ey0;
        const float w00 = ey0 - w01;
        const float w11 = fx * fyw;
        const float w10 = fyw - w11;

        // 3x ds_read2_b32 / tap: winA (l,l+1), winA (l+53,l+54), win2 (l,l+53)
        const float2 p00 = __half22float2(winA[l]);
        const float2 p01 = __half22float2(winA[l + 1]);
        const float2 p10 = __half22float2(winA[l + WCOLS]);
        const float2 p11 = __half22float2(winA[l + WCOLS + 1]);
        const float2 q0  = __half22float2(win2[l]);          // c2: x, x+1 @ row
        const float2 q1  = __half22float2(win2[l + WCOLS]);  // c2: x, x+1 @ row+1

        acc0 += w00 * p00.x + w01 * p01.x + w10 * p10.x + w11 * p11.x;
        acc1 += w00 * p00.y + w01 * p01.y + w10 * p10.y + w11 * p11.y;
        acc2 += w00 * q0.x  + w01 * q0.y  + w10 * q1.x  + w11 * q1.y;
    }

    const float occw = 1.0f / (1.0f + __expf(o_oth - o_own));
    const float wscale = occw / wsum;

    float* __restrict__ pt = part + ((size_t)(t * B_ + b) * C_) * HW_ + ij;
    pt[0]       = acc0 * wscale;
    pt[HW_]     = acc1 * wscale;
    pt[2 * HW_] = acc2 * wscale;
}

__global__ void combine2(const float4* __restrict__ part, float4* __restrict__ out) {
    const int n = blockIdx.x * blockDim.x + threadIdx.x;   // over BCHW/4
    const float4 p0 = part[n];
    const float4 p1 = part[n + BCHW_ / 4];
    float4 r;
    r.x = p0.x + p1.x; r.y = p0.y + p1.y; r.z = p0.z + p1.z; r.w = p0.w + p1.w;
    out[n] = r;
}

extern "C" void kernel_launch(void* const* d_in, const int* in_sizes, int n_in,
                              void* d_out, int out_size, void* d_ws, size_t ws_size,
                              hipStream_t stream) {
    const float* frames  = (const float*)d_in[0];
    const float* weights = (const float*)d_in[1];
    const float* alphas  = (const float*)d_in[2];
    const float* betas   = (const float*)d_in[3];
    const float* occl    = (const float*)d_in[4];
    float* out = (float*)d_out;
    float* part = (float*)d_ws;          // 6 MB; ws_size ample (verified R3+)

    const int blocks = B_ * T_ * NTILE;  // 2048
    adacof_tile<<<blocks, 256, 0, stream>>>(frames, weights, alphas, betas,
                                            occl, part);
    combine2<<<(BCHW_ / 4) / 256, 256, 0, stream>>>((const float4*)part,
                                                    (float4*)out);
}

// Round 16
// 38.803 us; speedup vs baseline: 1.0153x; 1.0153x over previous
//
#include <hip/hip_runtime.h>
#include <hip/hip_bf16.h>
#include <hip/hip_fp16.h>

// AdaCoF frame interpolation. R16: R15 + manual 5-deep ping-pong prefetch.
//  R15 post-mortem: conflicts -25% -> dur null => LDS off critical path.
//  VGPR=24 with a <=64-reg occupancy class (8 waves/SIMD) means 40 regs
//  unused and streaming (w,alpha,beta) loads issued ~1 tap ahead ->
//  L2/L3 latency exposed per tap. Fix: group taps by 5; while group P
//  computes, group P' (15 values) is loading. Buffers are 5-element arrays
//  indexed ONLY by literal constants after unroll (R3's spill was runtime
//  cur/nxt indexing; R6 proved static arrays -> VGPR 64, no spill).
//  Everything else R15 verbatim: fp16 winA(c0,c1) + pair-dup win2(c2,x/x+1),
//  3 ds_read2/tap, window-relative corner math, deferred normalization,
//  2048 blocks, ws partials + combine2.
//  Tripwires: VGPR <= 64 (class boundary), WRITE ~9 MB (no spill).

#define KS 5
#define K2 25
#define PADR 2

constexpr int T_ = 2;
constexpr int B_ = 4;
constexpr int C_ = 3;
constexpr int H_ = 256;
constexpr int W_ = 256;
constexpr int HW_ = H_ * W_;
constexpr int BCHW_ = B_ * C_ * HW_;                  // 786432
constexpr float HP_MAX = (float)(H_ + 2 * PADR - 1);  // 259
constexpr float WP_MAX = (float)(W_ + 2 * PADR - 1);  // 259
constexpr float HP_M2 = (float)(H_ + 2 * PADR - 2);   // 258
constexpr float WP_M2 = (float)(W_ + 2 * PADR - 2);   // 258

constexpr int TILE_W = 32;
constexpr int TILE_H = 8;
constexpr int HALO   = 8;
constexpr int RPAD   = HALO + PADR;            // 10
constexpr int WROWS  = TILE_H + 21;            // 29
constexpr int WCOLS  = TILE_W + 21;            // 53
constexpr int PLANE  = WROWS * WCOLS;          // 1537
constexpr int NTILE  = HW_ / (TILE_W * TILE_H);  // 256

__global__ __launch_bounds__(256) void adacof_tile(
    const float* __restrict__ frames,   // [T,B,C,H,W]
    const float* __restrict__ weights,  // [B,T,K2,H,W]
    const float* __restrict__ alphas,   // [B,T,K2,H,W]
    const float* __restrict__ betas,    // [B,T,K2,H,W]
    const float* __restrict__ occl,     // [B,T,H,W]
    float* __restrict__ part)           // ws: [T,B,C,H,W]
{
    __shared__ __half2 winA[PLANE];     // (c0,c1) at x:          6.1 KB
    __shared__ __half2 win2[PLANE];     // (c2 at x, c2 at x+1):  6.1 KB

    // block decode: 2048 blocks = b(4) x tile(256) x t(2)
    const int bid  = blockIdx.x;
    const int b    = bid >> 9;
    const int rem  = bid & 511;
    const int t    = rem & 1;
    const int tile = rem >> 1;          // 0..255
    const int i0   = (tile >> 3) << 3;  // row tile * 8
    const int j0   = (tile & 7) << 5;   // col tile * 32

    const int tid = threadIdx.x;
    const int wy0 = i0 - RPAD;
    const int wx0 = j0 - RPAD;

    const float* __restrict__ fb = frames + (size_t)(t * B_ + b) * C_ * HW_;

    // ---- stage window = materialized replication-padded image ----
    for (int e = tid; e < PLANE; e += 256) {
        const int wy = e / WCOLS;               // const-div -> magic mul
        const int wx = e - wy * WCOLS;
        const int gy  = min(max(wy0 + wy, 0), H_ - 1);
        const int gx  = min(max(wx0 + wx, 0), W_ - 1);
        const int gx1 = min(max(wx0 + wx + 1, 0), W_ - 1);
        const int gr = gy << 8;
        winA[e] = __floats2half2_rn(fb[gr + gx], fb[HW_ + gr + gx]);
        win2[e] = __floats2half2_rn(fb[2 * HW_ + gr + gx], fb[2 * HW_ + gr + gx1]);
    }

    const int x = tid & 31, r = tid >> 5;
    const int i = i0 + r, j = j0 + x;
    const int ij = (i << 8) | j;

    const int btbase = ((b * T_ + t) * K2) * HW_ + ij;
    const float* __restrict__ wp = weights + btbase;
    const float* __restrict__ ap = alphas + btbase;
    const float* __restrict__ bp = betas + btbase;

    // occlusion loads issued early, consumed in epilogue
    const float o_own = occl[(b * T_ + t) * HW_ + ij];
    const float o_oth = occl[(b * T_ + (1 - t)) * HW_ + ij];

    __syncthreads();

    float wsum = 0.0f, acc0 = 0.0f, acc1 = 0.0f, acc2 = 0.0f;
    const float fi = (float)i;
    const float fj = (float)j;
    const float oy = (float)(i0 - HALO);   // window-origin offset: wyr=y0f-oy
    const float ox = (float)(j0 - HALO);

    // ---- 5-deep ping-pong prefetch: group P' loads while P computes ----
    float wgA[5], agA[5], bgA[5];
    float wgB[5], agB[5], bgB[5];

#define PREFETCH(BUF, BASE)                                                    \
    {                                                                          \
        _Pragma("unroll")                                                      \
        for (int q = 0; q < 5; ++q) {                                          \
            wg##BUF[q] = wp[((BASE) + q) * HW_];                               \
            ag##BUF[q] = ap[((BASE) + q) * HW_];                               \
            bg##BUF[q] = bp[((BASE) + q) * HW_];                               \
        }                                                                      \
    }

#define TAP5(BUF, BASE)                                                        \
    {                                                                          \
        _Pragma("unroll")                                                      \
        for (int q = 0; q < 5; ++q) {                                          \
            const int k = (BASE) + q;                                          \
            const float ew = __expf(wg##BUF[q]);                               \
            wsum += ew;                                                        \
            const int kd = k / KS;                                             \
            const float dy = (float)kd;                                        \
            const float dx = (float)(k - kd * KS);                             \
            const float y2  = fminf(fmaxf(ag##BUF[q] + (dy + fi), 0.0f), HP_MAX); \
            const float x2  = fminf(fmaxf(bg##BUF[q] + (dx + fj), 0.0f), WP_MAX); \
            const float y0f = fminf(floorf(y2), HP_M2);                        \
            const float x0f = fminf(floorf(x2), WP_M2);                        \
            const float fy  = y2 - y0f;                                        \
            const float fx  = x2 - x0f;                                        \
            const int iy = (int)(y0f - oy);                                    \
            const int ixx = (int)(x0f - ox);                                   \
            const int l  = iy * WCOLS + ixx;                                   \
            const float fyw = fy * ew;                                         \
            const float ey0 = ew - fyw;                                        \
            const float w01 = fx * ey0;                                        \
            const float w00 = ey0 - w01;                                       \
            const float w11 = fx * fyw;                                        \
            const float w10 = fyw - w11;                                       \
            const float2 p00 = __half22float2(winA[l]);                        \
            const float2 p01 = __half22float2(winA[l + 1]);                    \
            const float2 p10 = __half22float2(winA[l + WCOLS]);                \
            const float2 p11 = __half22float2(winA[l + WCOLS + 1]);            \
            const float2 q0  = __half22float2(win2[l]);                        \
            const float2 q1  = __half22float2(win2[l + WCOLS]);                \
            acc0 += w00 * p00.x + w01 * p01.x + w10 * p10.x + w11 * p11.x;     \
            acc1 += w00 * p00.y + w01 * p01.y + w10 * p10.y + w11 * p11.y;     \
            acc2 += w00 * q0.x  + w01 * q0.y  + w10 * q1.x  + w11 * q1.y;      \
        }                                                                      \
    }

    PREFETCH(A, 0)      // group 0 in flight
    PREFETCH(B, 5)      // group 1 in flight
    TAP5(A, 0)          // compute 0 (covers its own waitcnt)
    PREFETCH(A, 10)     // group 2 in flight
    TAP5(B, 5)
    PREFETCH(B, 15)
    TAP5(A, 10)
    PREFETCH(A, 20)
    TAP5(B, 15)
    TAP5(A, 20)

#undef PREFETCH
#undef TAP5

    const float occw = 1.0f / (1.0f + __expf(o_oth - o_own));
    const float wscale = occw / wsum;

    float* __restrict__ pt = part + ((size_t)(t * B_ + b) * C_) * HW_ + ij;
    pt[0]       = acc0 * wscale;
    pt[HW_]     = acc1 * wscale;
    pt[2 * HW_] = acc2 * wscale;
}

__global__ void combine2(const float4* __restrict__ part, float4* __restrict__ out) {
    const int n = blockIdx.x * blockDim.x + threadIdx.x;   // over BCHW/4
    const float4 p0 = part[n];
    const float4 p1 = part[n + BCHW_ / 4];
    float4 r;
    r.x = p0.x + p1.x; r.y = p0.y + p1.y; r.z = p0.z + p1.z; r.w = p0.w + p1.w;
    out[n] = r;
}

extern "C" void kernel_launch(void* const* d_in, const int* in_sizes, int n_in,
                              void* d_out, int out_size, void* d_ws, size_t ws_size,
                              hipStream_t stream) {
    const float* frames  = (const float*)d_in[0];
    const float* weights = (const float*)d_in[1];
    const float* alphas  = (const float*)d_in[2];
    const float* betas   = (const float*)d_in[3];
    const float* occl    = (const float*)d_in[4];
    float* out = (float*)d_out;
    float* part = (float*)d_ws;          // 6 MB; ws_size ample (verified R3+)

    const int blocks = B_ * T_ * NTILE;  // 2048
    adacof_tile<<<blocks, 256, 0, stream>>>(frames, weights, alphas, betas,
                                            occl, part);
    combine2<<<(BCHW_ / 4) / 256, 256, 0, stream>>>((const float4*)part,
                                                    (float4*)out);
}